// Round 1
// baseline (3683.983 us; speedup 1.0000x reference)
//
#include <hip/hip_runtime.h>

// RNN: xp = x@Wx^T + b (GEMM, bf16 MFMA), then 512-step scan
// h_t = tanh(xp_t + h_{t-1}@Wh^T) with Wh register-resident in 4 groups of
// 16 WGs (16 batches x 64 j each), per-group device-scope flag barrier/step.
// xp is written into d_out and overwritten in place by h.

typedef unsigned short u16;
typedef __attribute__((ext_vector_type(4))) float f32x4;
typedef __attribute__((ext_vector_type(8))) short bf16x8;

__device__ __forceinline__ u16 f2bf(float f) {
  unsigned u = __builtin_bit_cast(unsigned, f);
  unsigned r = (u + 0x7fffu + ((u >> 16) & 1u)) >> 16;  // RTN-even
  return (u16)r;
}

__device__ __forceinline__ void async_cp16(u16* lds, const u16* g) {
  __builtin_amdgcn_global_load_lds(
      (const __attribute__((address_space(1))) unsigned int*)g,
      (__attribute__((address_space(3))) unsigned int*)lds, 16, 0, 0);
}

// ---------------- conversion kernels ----------------

__global__ __launch_bounds__(256) void conv_x_kernel(const float* __restrict__ in,
                                                     u16* __restrict__ outb) {
  const size_t i = (size_t)blockIdx.x * 256 + threadIdx.x;  // 8-elem chunk id
  const float4* p = (const float4*)(in + (i << 3));
  float4 a = p[0], b = p[1];
  bf16x8 v;
  v[0] = (short)f2bf(a.x); v[1] = (short)f2bf(a.y);
  v[2] = (short)f2bf(a.z); v[3] = (short)f2bf(a.w);
  v[4] = (short)f2bf(b.x); v[5] = (short)f2bf(b.y);
  v[6] = (short)f2bf(b.z); v[7] = (short)f2bf(b.w);
  *(bf16x8*)(outb + (i << 3)) = v;
}

__global__ __launch_bounds__(256) void conv_w_kernel(const float* __restrict__ W,
                                                     u16* __restrict__ Wx,
                                                     u16* __restrict__ Wh) {
  const int i = blockIdx.x * 256 + threadIdx.x;  // 8-elem chunk id, 2048/row
  const int j = i >> 8;          // row 0..1023
  const int c = (i & 255) << 3;  // col 0..2040
  const float4* p = (const float4*)(W + (size_t)j * 2048 + c);
  float4 a = p[0], b = p[1];
  bf16x8 v;
  v[0] = (short)f2bf(a.x); v[1] = (short)f2bf(a.y);
  v[2] = (short)f2bf(a.z); v[3] = (short)f2bf(a.w);
  v[4] = (short)f2bf(b.x); v[5] = (short)f2bf(b.y);
  v[6] = (short)f2bf(b.z); v[7] = (short)f2bf(b.w);
  u16* dst = (c < 1024) ? (Wx + (size_t)j * 1024 + c)
                        : (Wh + (size_t)j * 1024 + (c - 1024));
  *(bf16x8*)dst = v;
}

// ---------------- Phase 1: xp GEMM (m97 structure) ----------------
// C[m][n] = sum_k A[m][k]*B[n][k] + bias[n]; M=32768, N=K=1024.

__global__ __launch_bounds__(256, 2) void gemm_xp(const u16* __restrict__ A,
                                                  const u16* __restrict__ B,
                                                  const float* __restrict__ bias,
                                                  float* __restrict__ C) {
  const int bid = blockIdx.x;                    // 2048 blocks
  const int swz = (bid & 7) * 256 + (bid >> 3);  // XCD-aware swizzle (nwg%8==0)
  const int m0 = (swz >> 3) << 7;
  const int n0 = (swz & 7) << 7;
  const int tid = threadIdx.x;
  const int lane = tid & 63;
  const int wv = tid >> 6;
  const int mw = (wv >> 1) << 6;
  const int nw = (wv & 1) << 6;

  __shared__ __align__(16) u16 Alds[128 * 32];
  __shared__ __align__(16) u16 Blds[128 * 32];

  f32x4 acc[4][4] = {};

  for (int kt = 0; kt < 32; ++kt) {
    const int k0 = kt << 5;
#pragma unroll
    for (int i = 0; i < 2; ++i) {
      const int off = (i << 11) + (tid << 3);
      const int row = off >> 5;
      const int col = off & 31;
      async_cp16(&Alds[off], A + (size_t)(m0 + row) * 1024 + k0 + col);
      async_cp16(&Blds[off], B + (size_t)(n0 + row) * 1024 + k0 + col);
    }
    __syncthreads();  // drains vmcnt -> LDS ready
    bf16x8 af[4], bf[4];
#pragma unroll
    for (int mi = 0; mi < 4; ++mi)
      af[mi] = *(const bf16x8*)&Alds[((mw + (mi << 4) + (lane & 15)) << 5) +
                                     ((lane >> 4) << 3)];
#pragma unroll
    for (int ni = 0; ni < 4; ++ni)
      bf[ni] = *(const bf16x8*)&Blds[((nw + (ni << 4) + (lane & 15)) << 5) +
                                     ((lane >> 4) << 3)];
#pragma unroll
    for (int mi = 0; mi < 4; ++mi)
#pragma unroll
      for (int ni = 0; ni < 4; ++ni)
        acc[mi][ni] = __builtin_amdgcn_mfma_f32_16x16x32_bf16(
            af[mi], bf[ni], acc[mi][ni], 0, 0, 0);
    __syncthreads();
  }

  float bv[4];
#pragma unroll
  for (int ni = 0; ni < 4; ++ni)
    bv[ni] = bias[n0 + nw + (ni << 4) + (lane & 15)];
#pragma unroll
  for (int mi = 0; mi < 4; ++mi) {
#pragma unroll
    for (int r = 0; r < 4; ++r) {
      const int row = m0 + mw + (mi << 4) + ((lane >> 4) << 2) + r;
      float* cp = C + (size_t)row * 1024 + n0 + nw + (lane & 15);
#pragma unroll
      for (int ni = 0; ni < 4; ++ni) cp[ni << 4] = acc[mi][ni][r] + bv[ni];
    }
  }
}

// ---------------- Phase 2: recurrent scan ----------------
// 64 WGs = 4 groups x 16 WGs. Group g: batches [16g,16g+16). WG wloc: j-slice
// [64*wloc, +64). Wave wv: 16 j. Wh slice persistent in VGPRs (32 B-frags).
// Per step: group barrier (device-scope counter), stage H slice (32KB) into
// subtiled+swizzled LDS, 32 MFMAs, tanh, write h (fp32 to out, bf16 to Hbuf).

__global__ __launch_bounds__(256, 1) void rnn_scan(float* __restrict__ out,
                                                   const u16* __restrict__ Wh,
                                                   u16* __restrict__ Hbuf,
                                                   unsigned* __restrict__ counters) {
  const int wg = blockIdx.x;   // 0..63
  const int g = wg & 3;        // group; WGs of a group land on XCDs {g, g+4}
  const int wloc = wg >> 2;    // 0..15
  const int b0 = g << 4;
  const int tid = threadIdx.x;
  const int lane = tid & 63;
  const int wv = tid >> 6;
  const int jw = (wloc << 6) + (wv << 4);  // wave's j base

  __shared__ __align__(16) u16 Hlds[16384];  // 32KB, subtiled layout
  char* ldsb = (char*)Hlds;

  // Persistent weight fragments: B[k][n] = Wh[j=n][i=k]
  bf16x8 bfrag[32];
  {
    const u16* wp = Wh + (size_t)(jw + (lane & 15)) * 1024 + ((lane >> 4) << 3);
#pragma unroll
    for (int kk = 0; kk < 32; ++kk) bfrag[kk] = *(const bf16x8*)(wp + kk * 32);
  }

  unsigned* cnt = counters + (g << 6);  // 256B-spaced per group
  const int colj = jw + (lane & 15);
  const int rbase = b0 + ((lane >> 4) << 2);

#pragma unroll 1
  for (int t = 0; t < 512; ++t) {
    f32x4 acc0 = {0.f, 0.f, 0.f, 0.f};
    f32x4 acc1 = {0.f, 0.f, 0.f, 0.f};
    if (t > 0) {
      if (tid == 0) {
        const unsigned target = (unsigned)(t << 4);
        while (__hip_atomic_load(cnt, __ATOMIC_ACQUIRE,
                                 __HIP_MEMORY_SCOPE_AGENT) < target)
          __builtin_amdgcn_s_sleep(1);
      }
      __syncthreads();
      __builtin_amdgcn_fence(__ATOMIC_ACQUIRE, "agent");  // order + L1/L2 inv

      // stage H[(t-1)&1][b0..b0+16][0..1024) -> LDS subtiles
      {
        const u16* Hsrc = Hbuf + (((t - 1) & 1) << 16) + (b0 << 10);
        const int sb = tid & 15, sc = tid >> 4;
        const u16* hs = Hsrc + (sb << 10) + (sc << 6);  // 128B contiguous
#pragma unroll
        for (int p = 0; p < 8; ++p) {
          bf16x8 v = *(const bf16x8*)(hs + (p << 3));
          const int kk = (sc << 1) + (p >> 2);
          const int kg = p & 3;
          const int bb = sb ^ ((kk >> 1) & 7);  // bank swizzle
          *(bf16x8*)(ldsb + (kk << 10) + (kg << 8) + (bb << 4)) = v;
        }
      }
      __syncthreads();

      const int myb = lane & 15;
      const int kgoff = (lane >> 4) << 8;
#pragma unroll
      for (int kk2 = 0; kk2 < 16; ++kk2) {
        const int k0 = kk2 * 2, k1 = kk2 * 2 + 1;
        bf16x8 a0 = *(const bf16x8*)(ldsb + (k0 << 10) + kgoff +
                                     ((myb ^ ((k0 >> 1) & 7)) << 4));
        bf16x8 a1 = *(const bf16x8*)(ldsb + (k1 << 10) + kgoff +
                                     ((myb ^ ((k1 >> 1) & 7)) << 4));
        acc0 = __builtin_amdgcn_mfma_f32_16x16x32_bf16(a0, bfrag[k0], acc0, 0, 0, 0);
        acc1 = __builtin_amdgcn_mfma_f32_16x16x32_bf16(a1, bfrag[k1], acc1, 0, 0, 0);
      }
    }

    // epilogue: h = tanh(xp + acc); out <- h (fp32), Hbuf[t&1] <- h (bf16)
    u16* Hdst = Hbuf + ((t & 1) << 16);
#pragma unroll
    for (int r = 0; r < 4; ++r) {
      const int brow = rbase + r;
      const size_t oidx = ((size_t)brow * 512 + t) * 1024 + colj;
      float v = out[oidx] + acc0[r] + acc1[r];
      v = tanhf(v);
      out[oidx] = v;
      Hdst[((size_t)brow << 10) + colj] = f2bf(v);
    }
    __syncthreads();  // drain all waves' stores (+ LDS reads) before publish
    if (tid == 0)
      __hip_atomic_fetch_add(cnt, 1u, __ATOMIC_RELEASE,
                             __HIP_MEMORY_SCOPE_AGENT);  // wbl2 + add
  }
}

// ---------------- launcher ----------------

extern "C" void kernel_launch(void* const* d_in, const int* in_sizes, int n_in,
                              void* d_out, int out_size, void* d_ws,
                              size_t ws_size, hipStream_t stream) {
  const float* x = (const float*)d_in[0];     // [64][512][1024]
  const float* W = (const float*)d_in[1];     // [1024][2048]
  const float* bias = (const float*)d_in[2];  // [1024]
  float* out = (float*)d_out;                 // [64][512][1024]

  char* ws = (char*)d_ws;
  u16* xb = (u16*)ws;                           // 67,108,864 B
  u16* Wxb = (u16*)(ws + 67108864);             //  2,097,152 B
  u16* Whb = (u16*)(ws + 69206016);             //  2,097,152 B
  u16* Hbuf = (u16*)(ws + 71303168);            //    262,144 B
  unsigned* counters = (unsigned*)(ws + 71565312);  // 1,024 B

  hipMemsetAsync(counters, 0, 1024, stream);
  conv_x_kernel<<<16384, 256, 0, stream>>>(x, xb);
  conv_w_kernel<<<1024, 256, 0, stream>>>(W, Wxb, Whb);
  gemm_xp<<<2048, 256, 0, stream>>>(xb, Wxb, bias, out);
  rnn_scan<<<64, 256, 0, stream>>>(out, Whb, Hbuf, counters);
}

// Round 3
// 2194.742 us; speedup vs baseline: 1.6785x; 1.6785x over previous
//
#include <hip/hip_runtime.h>

// RNN: xp = x@Wx^T + b (GEMM, bf16 MFMA), then 512-step scan
// h_t = tanh(xp_t + h_{t-1}@Wh^T).
// Scan: 4 groups x 16 WGs (16 batches x 64 j each). Wh register-resident.
// Swapped MFMA operands (A=Wh j-rows, B=h batch-rows) so each thread owns 4
// consecutive j for one batch. Cross-WG exchange via L3 (relaxed agent-scope
// atomics, NO fences -> no per-step L2 writeback/invalidate).
// Waves K-split (256 k each); partial sums reduced via LDS (double-buffered).

typedef unsigned short u16;
typedef unsigned long long u64;
typedef __attribute__((ext_vector_type(4))) float f32x4;
typedef __attribute__((ext_vector_type(8))) short bf16x8;

__device__ __forceinline__ u16 f2bf(float f) {
  unsigned u = __builtin_bit_cast(unsigned, f);
  unsigned r = (u + 0x7fffu + ((u >> 16) & 1u)) >> 16;  // RTN-even
  return (u16)r;
}

__device__ __forceinline__ void async_cp16(u16* lds, const u16* g) {
  __builtin_amdgcn_global_load_lds(
      (const __attribute__((address_space(1))) unsigned int*)g,
      (__attribute__((address_space(3))) unsigned int*)lds, 16, 0, 0);
}

// ---------------- conversion kernels ----------------

__global__ __launch_bounds__(256) void conv_x_kernel(const float* __restrict__ in,
                                                     u16* __restrict__ outb) {
  const size_t i = (size_t)blockIdx.x * 256 + threadIdx.x;  // 8-elem chunk id
  const float4* p = (const float4*)(in + (i << 3));
  float4 a = p[0], b = p[1];
  bf16x8 v;
  v[0] = (short)f2bf(a.x); v[1] = (short)f2bf(a.y);
  v[2] = (short)f2bf(a.z); v[3] = (short)f2bf(a.w);
  v[4] = (short)f2bf(b.x); v[5] = (short)f2bf(b.y);
  v[6] = (short)f2bf(b.z); v[7] = (short)f2bf(b.w);
  *(bf16x8*)(outb + (i << 3)) = v;
}

__global__ __launch_bounds__(256) void conv_w_kernel(const float* __restrict__ W,
                                                     u16* __restrict__ Wx,
                                                     u16* __restrict__ Wh) {
  const int i = blockIdx.x * 256 + threadIdx.x;  // 8-elem chunk id, 2048/row
  const int j = i >> 8;          // row 0..1023
  const int c = (i & 255) << 3;  // col 0..2040
  const float4* p = (const float4*)(W + (size_t)j * 2048 + c);
  float4 a = p[0], b = p[1];
  bf16x8 v;
  v[0] = (short)f2bf(a.x); v[1] = (short)f2bf(a.y);
  v[2] = (short)f2bf(a.z); v[3] = (short)f2bf(a.w);
  v[4] = (short)f2bf(b.x); v[5] = (short)f2bf(b.y);
  v[6] = (short)f2bf(b.z); v[7] = (short)f2bf(b.w);
  u16* dst = (c < 1024) ? (Wx + (size_t)j * 1024 + c)
                        : (Wh + (size_t)j * 1024 + (c - 1024));
  *(bf16x8*)dst = v;
}

// ---------------- Phase 1: xp GEMM (m97 structure) ----------------
// C[m][n] = sum_k A[m][k]*B[n][k] + bias[n]; M=32768, N=K=1024.

__global__ __launch_bounds__(256, 2) void gemm_xp(const u16* __restrict__ A,
                                                  const u16* __restrict__ B,
                                                  const float* __restrict__ bias,
                                                  float* __restrict__ C) {
  const int bid = blockIdx.x;                    // 2048 blocks
  const int swz = (bid & 7) * 256 + (bid >> 3);  // XCD-aware swizzle (nwg%8==0)
  const int m0 = (swz >> 3) << 7;
  const int n0 = (swz & 7) << 7;
  const int tid = threadIdx.x;
  const int lane = tid & 63;
  const int wv = tid >> 6;
  const int mw = (wv >> 1) << 6;
  const int nw = (wv & 1) << 6;

  __shared__ __align__(16) u16 Alds[128 * 32];
  __shared__ __align__(16) u16 Blds[128 * 32];

  f32x4 acc[4][4] = {};

  for (int kt = 0; kt < 32; ++kt) {
    const int k0 = kt << 5;
#pragma unroll
    for (int i = 0; i < 2; ++i) {
      const int off = (i << 11) + (tid << 3);
      const int row = off >> 5;
      const int col = off & 31;
      async_cp16(&Alds[off], A + (size_t)(m0 + row) * 1024 + k0 + col);
      async_cp16(&Blds[off], B + (size_t)(n0 + row) * 1024 + k0 + col);
    }
    __syncthreads();  // drains vmcnt -> LDS ready
    bf16x8 af[4], bf[4];
#pragma unroll
    for (int mi = 0; mi < 4; ++mi)
      af[mi] = *(const bf16x8*)&Alds[((mw + (mi << 4) + (lane & 15)) << 5) +
                                     ((lane >> 4) << 3)];
#pragma unroll
    for (int ni = 0; ni < 4; ++ni)
      bf[ni] = *(const bf16x8*)&Blds[((nw + (ni << 4) + (lane & 15)) << 5) +
                                     ((lane >> 4) << 3)];
#pragma unroll
    for (int mi = 0; mi < 4; ++mi)
#pragma unroll
      for (int ni = 0; ni < 4; ++ni)
        acc[mi][ni] = __builtin_amdgcn_mfma_f32_16x16x32_bf16(
            af[mi], bf[ni], acc[mi][ni], 0, 0, 0);
    __syncthreads();
  }

  float bv[4];
#pragma unroll
  for (int ni = 0; ni < 4; ++ni)
    bv[ni] = bias[n0 + nw + (ni << 4) + (lane & 15)];
#pragma unroll
  for (int mi = 0; mi < 4; ++mi) {
#pragma unroll
    for (int r = 0; r < 4; ++r) {
      const int row = m0 + mw + (mi << 4) + ((lane >> 4) << 2) + r;
      float* cp = C + (size_t)row * 1024 + n0 + nw + (lane & 15);
#pragma unroll
      for (int ni = 0; ni < 4; ++ni) cp[ni << 4] = acc[mi][ni][r] + bv[ni];
    }
  }
}

// ---------------- Phase 2: recurrent scan ----------------
// WG (g, wloc): batches [16g,16g+16), j in [64*wloc, +64). Wave wv: k-slice
// [256wv,+256), holds A=Wh[64 j][256 k] in VGPRs, computes partial acc for
// 4 j-tiles; LDS reduce reassigns wave wv -> j-tile wv. Per wave: 8B atomic
// h store -> vmcnt(0) -> flag store. Consumers poll 64 flags then load h
// fragments straight from L3 into MFMA B-frags.

__global__ __launch_bounds__(256, 1) void rnn_scan(float* __restrict__ out,
                                                   const u16* __restrict__ Wh,
                                                   u64* __restrict__ H64,
                                                   unsigned* __restrict__ flags) {
  const int wg = blockIdx.x;   // 0..63
  const int g = wg & 3;        // group (16 batches)
  const int wloc = wg >> 2;    // 0..15 (j-slice)
  const int b0 = g << 4;
  const int tid = threadIdx.x;
  const int lane = tid & 63;
  const int wv = tid >> 6;     // k-slice owner, then j-tile owner
  const int J0 = wloc << 6;
  const int l16 = lane & 15;
  const int lhi = lane >> 4;

  __shared__ __align__(16) float red[2][16][64][4];  // 32KB, dbuf

  // A-frags: Wh[J0 + jt*16 + l16][wv*256 + kk*32 + lhi*8 .. +8]
  bf16x8 af[4][8];
  {
    const u16* wp = Wh + (size_t)(J0 + l16) * 1024 + (wv << 8) + (lhi << 3);
#pragma unroll
    for (int jt = 0; jt < 4; ++jt)
#pragma unroll
      for (int kk = 0; kk < 8; ++kk)
        af[jt][kk] = *(const bf16x8*)(wp + (jt << 14) + (kk << 5));
  }

  unsigned* gflags = flags + (g << 6);               // 64 flags per group
  const int jbase = J0 + (wv << 4) + (lhi << 2);     // 4 consecutive j owned
  float* pout = out + ((size_t)(b0 + l16) << 19) + jbase;  // (b*512*1024)+j
  const int hw = ((b0 + l16) << 8) + (jbase >> 2);   // u64 idx of own h store
  const int hr = ((b0 + l16) << 8) + (wv << 6) + (lhi << 1);  // b-frag base

  f32x4 xp = __builtin_nontemporal_load((const f32x4*)pout);  // t=0 prefetch

#pragma unroll 1
  for (int t = 0; t < 512; ++t) {
    f32x4 acc[4] = {};
    if (t > 0) {
      const unsigned tgt = (unsigned)t;
      while (true) {
        unsigned v = __hip_atomic_load(&gflags[lane], __ATOMIC_RELAXED,
                                       __HIP_MEMORY_SCOPE_AGENT);
        if (__all((int)(v >= tgt))) break;
      }
      const u64* Hs = H64 + (((t - 1) & 1) << 14) + hr;
      u64 q[16];
#pragma unroll
      for (int kk = 0; kk < 8; ++kk) {
        q[2 * kk] = __hip_atomic_load(Hs + (kk << 3), __ATOMIC_RELAXED,
                                      __HIP_MEMORY_SCOPE_AGENT);
        q[2 * kk + 1] = __hip_atomic_load(Hs + (kk << 3) + 1, __ATOMIC_RELAXED,
                                          __HIP_MEMORY_SCOPE_AGENT);
      }
#pragma unroll
      for (int kk = 0; kk < 8; ++kk) {
        union { u64 qq[2]; bf16x8 v; } u;
        u.qq[0] = q[2 * kk];
        u.qq[1] = q[2 * kk + 1];
#pragma unroll
        for (int jt = 0; jt < 4; ++jt)
          acc[jt] = __builtin_amdgcn_mfma_f32_16x16x32_bf16(af[jt][kk], u.v,
                                                            acc[jt], 0, 0, 0);
      }
    }
    // cross-wave K-reduction via LDS (one barrier; buffers alternate by t&1)
    const int rb = t & 1;
#pragma unroll
    for (int jt = 0; jt < 4; ++jt)
      *(f32x4*)&red[rb][(wv << 2) + jt][lane][0] = acc[jt];
    __syncthreads();
    f32x4 s = *(const f32x4*)&red[rb][wv][lane][0];
#pragma unroll
    for (int w = 1; w < 4; ++w)
      s += *(const f32x4*)&red[rb][(w << 2) + wv][lane][0];

    const float h0 = tanhf(xp[0] + s[0]);
    const float h1 = tanhf(xp[1] + s[1]);
    const float h2 = tanhf(xp[2] + s[2]);
    const float h3 = tanhf(xp[3] + s[3]);

    const u64 pack = (u64)f2bf(h0) | ((u64)f2bf(h1) << 16) |
                     ((u64)f2bf(h2) << 32) | ((u64)f2bf(h3) << 48);
    __hip_atomic_store(H64 + ((t & 1) << 14) + hw, pack, __ATOMIC_RELAXED,
                       __HIP_MEMORY_SCOPE_AGENT);
    asm volatile("s_waitcnt vmcnt(0)" ::: "memory");  // h visible at L3
    if (lane == 0)
      __hip_atomic_store(&gflags[(wloc << 2) + wv], (unsigned)(t + 1),
                         __ATOMIC_RELAXED, __HIP_MEMORY_SCOPE_AGENT);
    // fire-and-forget after publish
    f32x4 hv;
    hv[0] = h0; hv[1] = h1; hv[2] = h2; hv[3] = h3;
    __builtin_nontemporal_store(hv, (f32x4*)(pout + ((size_t)t << 10)));
    if (t < 511)
      xp = __builtin_nontemporal_load(
          (const f32x4*)(pout + ((size_t)(t + 1) << 10)));
  }
}

// ---------------- launcher ----------------

extern "C" void kernel_launch(void* const* d_in, const int* in_sizes, int n_in,
                              void* d_out, int out_size, void* d_ws,
                              size_t ws_size, hipStream_t stream) {
  const float* x = (const float*)d_in[0];     // [64][512][1024]
  const float* W = (const float*)d_in[1];     // [1024][2048]
  const float* bias = (const float*)d_in[2];  // [1024]
  float* out = (float*)d_out;                 // [64][512][1024]

  char* ws = (char*)d_ws;
  u16* xb = (u16*)ws;                           // 67,108,864 B
  u16* Wxb = (u16*)(ws + 67108864);             //  2,097,152 B
  u16* Whb = (u16*)(ws + 69206016);             //  2,097,152 B
  u64* Hbuf = (u64*)(ws + 71303168);            //    262,144 B (2 x 64 x 1024 bf16)
  unsigned* flags = (unsigned*)(ws + 71565312); //      1,024 B

  (void)hipMemsetAsync(flags, 0, 1024, stream);
  conv_x_kernel<<<16384, 256, 0, stream>>>(x, xb);
  conv_w_kernel<<<1024, 256, 0, stream>>>(W, Wxb, Whb);
  gemm_xp<<<2048, 256, 0, stream>>>(xb, Wxb, bias, out);
  rnn_scan<<<64, 256, 0, stream>>>(out, Whb, Hbuf, flags);
}